// Round 4
// baseline (302.214 us; speedup 1.0000x reference)
//
#include <hip/hip_runtime.h>
#include <stdint.h>

typedef unsigned short u16;

#define MTOK 4096
#define CIN  3072
#define COUT 3072
#define RANK 32
#define KT48 48
#define LKSPLIT 8
#define LKC (CIN/LKSPLIT)   // 384

// prep grid: [0,LORA_BLK) lora partials, then quant rows, then wdq rows
#define LORA_BLK 256            // 32 m-panels x 8 K-splits
#define QUANT_BLK MTOK          // 4096 (one token row per block)
#define WDQ_BLK COUT            // 3072

// Workspace:
//   xdq:   (MTOK, CIN) bf16   pure quantized activations (row stride 6144 B, pow2-friendly)
//   wdq:   (COUT, CIN) bf16   pure dequantized weights
//   pu_bf: (COUT, RANK) bf16  proj_up cast
//   lp:    (LKSPLIT, MTOK, RANK) f32  lora K-split partials (deterministic)

typedef __attribute__((ext_vector_type(8))) short bf16x8;
typedef __attribute__((ext_vector_type(4))) float f32x4;

__device__ __forceinline__ u16 f2bf(float f) {
  union { float f; unsigned u; } v; v.f = f;
  unsigned r = v.u + 0x7FFFu + ((v.u >> 16) & 1u);  // RNE
  return (u16)(r >> 16);
}

__device__ __forceinline__ void gload_lds16(const void* g, void* l) {
  __builtin_amdgcn_global_load_lds(
      (const __attribute__((address_space(1))) unsigned int*)g,
      (__attribute__((address_space(3))) unsigned int*)l, 16, 0, 0);
}

__device__ __forceinline__ float quant1(float xs, float ascale, float qd) {
  float q = rintf(xs / qd);                      // jnp.round = RNE, exact IEEE div
  q = fminf(fmaxf(q, -8.f), 7.f);
  return q * ascale;
}

// Fused prep: lora partial GEMM blocks + activation quant rows + weight dequant rows.
__global__ __launch_bounds__(256) void prep_kernel(
    const float* __restrict__ x, const float* __restrict__ smooth,
    const int* __restrict__ qw, const float* __restrict__ wsc,
    const float* __restrict__ pd, const float* __restrict__ pu,
    u16* __restrict__ xdq, u16* __restrict__ wdq, u16* __restrict__ pu_bf,
    float* __restrict__ lp)
{
  const int b = blockIdx.x;
  const int t = threadIdx.x;

  if (b < LORA_BLK) {
    // ---- lora partial: lora_act[m0..m0+128) for K-chunk kblk -> lp ----
    __shared__ __align__(16) u16 sA[128 * 64];
    __shared__ __align__(16) u16 sB[32 * 64];
    const int m0 = (b >> 3) * 128;        // 32 m-blocks
    const int kblk = b & 7;               // 8 K-splits
    const int wave = t >> 6, lane = t & 63;
    const int lm = lane & 15, lkq = (lane >> 4) * 8;

    f32x4 acc[2][2];
    const f32x4 fz = {0.f, 0.f, 0.f, 0.f};
#pragma unroll
    for (int i = 0; i < 2; ++i)
#pragma unroll
      for (int j = 0; j < 2; ++j) acc[i][j] = fz;

    for (int kt = 0; kt < LKC / 64; ++kt) {
      const int k0 = kblk * LKC + kt * 64;
#pragma unroll
      for (int it = 0; it < 8; ++it) {
        const int row = it * 16 + (t >> 4);
        const int col = (t & 15) * 4;
        const float4 xv = *(const float4*)(x + (size_t)(m0 + row) * CIN + k0 + col);
        const float4 sv = *(const float4*)(smooth + k0 + col);
        ushort4 ov;
        ov.x = f2bf(xv.x / sv.x);
        ov.y = f2bf(xv.y / sv.y);
        ov.z = f2bf(xv.z / sv.z);
        ov.w = f2bf(xv.w / sv.w);
        *(ushort4*)&sA[row * 64 + col] = ov;
      }
#pragma unroll
      for (int i = 0; i < 8; ++i) {
        const int idx = i * 256 + t;
        const int k = idx >> 5, r = idx & 31;
        sB[r * 64 + k] = f2bf(pd[(size_t)(k0 + k) * RANK + r]);
      }
      __syncthreads();
#pragma unroll
      for (int kk = 0; kk < 2; ++kk) {
        const int ko = kk * 32 + lkq;
        bf16x8 af[2], bfr[2];
#pragma unroll
        for (int i = 0; i < 2; ++i)
          af[i] = *(const bf16x8*)&sA[(wave * 32 + i * 16 + lm) * 64 + ko];
#pragma unroll
        for (int j = 0; j < 2; ++j)
          bfr[j] = *(const bf16x8*)&sB[(j * 16 + lm) * 64 + ko];
#pragma unroll
        for (int i = 0; i < 2; ++i)
#pragma unroll
          for (int j = 0; j < 2; ++j)
            acc[i][j] = __builtin_amdgcn_mfma_f32_16x16x32_bf16(af[i], bfr[j], acc[i][j], 0, 0, 0);
      }
      __syncthreads();
    }
    float* lpk = lp + (size_t)kblk * MTOK * RANK;
#pragma unroll
    for (int i = 0; i < 2; ++i)
#pragma unroll
      for (int j = 0; j < 2; ++j) {
        const int col = j * 16 + lm;
        const int row0 = m0 + wave * 32 + i * 16 + (lane >> 4) * 4;
#pragma unroll
        for (int r = 0; r < 4; ++r)
          lpk[(size_t)(row0 + r) * RANK + col] = acc[i][j][r];
      }
  } else if (b < LORA_BLK + QUANT_BLK) {
    // ---- activation quant: one row, 3 float4/thread, 16 lanes = one 64-group ----
    const int m = b - LORA_BLK;
    const float* xr = x + (size_t)m * CIN;
    u16* orow = xdq + (size_t)m * CIN;
    const int c = t * 4;
    float4 xv0 = *(const float4*)(xr + c);
    float4 xv1 = *(const float4*)(xr + 1024 + c);
    float4 xv2 = *(const float4*)(xr + 2048 + c);
    const float4 sv0 = *(const float4*)(smooth + c);
    const float4 sv1 = *(const float4*)(smooth + 1024 + c);
    const float4 sv2 = *(const float4*)(smooth + 2048 + c);
    float4 xs[3];
    xs[0] = make_float4(xv0.x / sv0.x, xv0.y / sv0.y, xv0.z / sv0.z, xv0.w / sv0.w);
    xs[1] = make_float4(xv1.x / sv1.x, xv1.y / sv1.y, xv1.z / sv1.z, xv1.w / sv1.w);
    xs[2] = make_float4(xv2.x / sv2.x, xv2.y / sv2.y, xv2.z / sv2.z, xv2.w / sv2.w);
#pragma unroll
    for (int p = 0; p < 3; ++p) {
      float a = fmaxf(fmaxf(fabsf(xs[p].x), fabsf(xs[p].y)),
                      fmaxf(fabsf(xs[p].z), fabsf(xs[p].w)));
#pragma unroll
      for (int off = 1; off < 16; off <<= 1) a = fmaxf(a, __shfl_xor(a, off));
      const float ascale = a / 7.0f;
      const float qd = fmaxf(ascale, 1e-8f);
      ushort4 o;
      o.x = f2bf(quant1(xs[p].x, ascale, qd));
      o.y = f2bf(quant1(xs[p].y, ascale, qd));
      o.z = f2bf(quant1(xs[p].z, ascale, qd));
      o.w = f2bf(quant1(xs[p].w, ascale, qd));
      *(ushort4*)(orow + p * 1024 + c) = o;
    }
  } else {
    // ---- weight dequant row + pu_bf cast ----
    const int o = b - LORA_BLK - QUANT_BLK;
    const int4* qrow = (const int4*)(qw + (size_t)o * CIN);
    u16* orow = wdq + (size_t)o * CIN;
#pragma unroll
    for (int p = 0; p < 3; ++p) {
      const int c4 = p * 256 + t;
      const int g = (c4 * 4) >> 6;
      const float ws = wsc[g * COUT + o];    // wscales is (G, C_out)
      const int4 qv = qrow[c4];
      ushort4 ov;
      ov.x = f2bf((float)(qv.x - 8) * ws);
      ov.y = f2bf((float)(qv.y - 8) * ws);
      ov.z = f2bf((float)(qv.z - 8) * ws);
      ov.w = f2bf((float)(qv.w - 8) * ws);
      ((ushort4*)orow)[c4] = ov;
    }
    if (t < RANK) pu_bf[(size_t)o * RANK + t] = f2bf(pu[(size_t)o * RANK + t]);
  }
}

// Main GEMM: 128x128 bf16 MFMA, K=3072, XOR-swizzled LDS, lora+bias epilogue.
__global__ __launch_bounds__(256) void gemm_kernel(
    const u16* __restrict__ xdq, const u16* __restrict__ wdq,
    const u16* __restrict__ pu_bf, const float* __restrict__ lp,
    const float* __restrict__ bias, float* __restrict__ out)
{
  __shared__ __align__(16) u16 sA[128 * 64];
  __shared__ __align__(16) u16 sB[128 * 64];
  const int t = threadIdx.x;
  const int wave = t >> 6, lane = t & 63;
  const int wm = wave >> 1, wn = wave & 1;           // 2x2 wave grid, 64x64 each
  const int m0 = blockIdx.y * 128, n0 = blockIdx.x * 128;
  const int lrow = lane >> 3;                        // 0..7 row within 8-row chunk
  const int gcol = ((lane & 7) ^ lrow) * 8;          // swizzled global col block

  f32x4 acc[4][4];
  const f32x4 fz = {0.f, 0.f, 0.f, 0.f};
#pragma unroll
  for (int i = 0; i < 4; ++i)
#pragma unroll
    for (int j = 0; j < 4; ++j) acc[i][j] = fz;

  const int lm = lane & 15;
  const int xs7 = lm & 7;                            // row&7 for fragment rows
  const int q4 = lane >> 4;

  for (int kt = 0; kt < KT48; ++kt) {
    const u16* Ab = xdq + (size_t)m0 * CIN + kt * 64;
    const u16* Bb = wdq + (size_t)n0 * CIN + kt * 64;
#pragma unroll
    for (int r = 0; r < 4; ++r) {
      const int ci = wave * 4 + r;                   // 1KB chunk id (16 per tile)
      const int row = ci * 8 + lrow;
      gload_lds16(Ab + (size_t)row * CIN + gcol, &sA[ci * 512 + lane * 8]);
      gload_lds16(Bb + (size_t)row * CIN + gcol, &sB[ci * 512 + lane * 8]);
    }
    __syncthreads();   // drains vmcnt incl. global_load_lds
#pragma unroll
    for (int kk = 0; kk < 2; ++kk) {
      const int csw = ((kk * 4 + q4) ^ xs7) * 8;     // swizzled LDS col for this k-block
      bf16x8 af[4], bfr[4];
#pragma unroll
      for (int i = 0; i < 4; ++i)
        af[i] = *(const bf16x8*)&sA[(wm * 64 + i * 16 + lm) * 64 + csw];
#pragma unroll
      for (int j = 0; j < 4; ++j)
        bfr[j] = *(const bf16x8*)&sB[(wn * 64 + j * 16 + lm) * 64 + csw];
#pragma unroll
      for (int i = 0; i < 4; ++i)
#pragma unroll
        for (int j = 0; j < 4; ++j)
          acc[i][j] = __builtin_amdgcn_mfma_f32_16x16x32_bf16(af[i], bfr[j], acc[i][j], 0, 0, 0);
    }
    __syncthreads();
  }

  // ---- lora epilogue: acc += lora_act(128x32) . proj_up(128x32)^T ----
  // A-frag [m=lm][k=q4*8+jj]: lora_act summed from 8 K-split partials, packed bf16.
  bf16x8 afl[4], bfl[4];
#pragma unroll
  for (int i = 0; i < 4; ++i) {
    const int arow = m0 + wm * 64 + i * 16 + lm;
    float s0 = 0.f, s1 = 0.f, s2 = 0.f, s3 = 0.f;
    float s4 = 0.f, s5 = 0.f, s6 = 0.f, s7 = 0.f;
#pragma unroll
    for (int sp = 0; sp < LKSPLIT; ++sp) {
      const float4* pp = (const float4*)(lp + ((size_t)sp * MTOK + arow) * RANK + q4 * 8);
      const float4 a0 = pp[0], a1 = pp[1];
      s0 += a0.x; s1 += a0.y; s2 += a0.z; s3 += a0.w;
      s4 += a1.x; s5 += a1.y; s6 += a1.z; s7 += a1.w;
    }
    union { bf16x8 v; u16 u[8]; } pk;
    pk.u[0] = f2bf(s0); pk.u[1] = f2bf(s1); pk.u[2] = f2bf(s2); pk.u[3] = f2bf(s3);
    pk.u[4] = f2bf(s4); pk.u[5] = f2bf(s5); pk.u[6] = f2bf(s6); pk.u[7] = f2bf(s7);
    afl[i] = pk.v;
  }
#pragma unroll
  for (int j = 0; j < 4; ++j) {
    const int bcol = n0 + wn * 64 + j * 16 + lm;
    bfl[j] = *(const bf16x8*)(pu_bf + (size_t)bcol * RANK + q4 * 8);
  }
#pragma unroll
  for (int i = 0; i < 4; ++i)
#pragma unroll
    for (int j = 0; j < 4; ++j)
      acc[i][j] = __builtin_amdgcn_mfma_f32_16x16x32_bf16(afl[i], bfl[j], acc[i][j], 0, 0, 0);

  // epilogue: C/D layout col=lane&15, row=(lane>>4)*4+reg  [m89-verified]
#pragma unroll
  for (int j = 0; j < 4; ++j) {
    const int col = n0 + wn * 64 + j * 16 + lm;
    const float bv = bias[col];
#pragma unroll
    for (int i = 0; i < 4; ++i) {
      const int row0 = m0 + wm * 64 + i * 16 + (lane >> 4) * 4;
#pragma unroll
      for (int r = 0; r < 4; ++r)
        out[(size_t)(row0 + r) * COUT + col] = acc[i][j][r] + bv;
    }
  }
}

extern "C" void kernel_launch(void* const* d_in, const int* in_sizes, int n_in,
                              void* d_out, int out_size, void* d_ws, size_t ws_size,
                              hipStream_t stream) {
  const float* x      = (const float*)d_in[0];
  const int*   qw     = (const int*)d_in[1];
  const float* wsc    = (const float*)d_in[2];
  const float* smooth = (const float*)d_in[3];
  const float* pd     = (const float*)d_in[4];
  const float* pu     = (const float*)d_in[5];
  const float* bias   = (const float*)d_in[6];
  float* out = (float*)d_out;

  u16* xdq   = (u16*)d_ws;                              // 4096*3072*2 = 25.2 MB
  u16* wdq   = xdq + (size_t)MTOK * CIN;                // 3072*3072*2 = 18.9 MB
  u16* pu_bf = wdq + (size_t)COUT * CIN;                // 3072*32*2   = 0.2 MB
  float* lp  = (float*)(pu_bf + (size_t)COUT * RANK);   // 8*4096*32*4 = 4.2 MB

  prep_kernel<<<LORA_BLK + QUANT_BLK + WDQ_BLK, 256, 0, stream>>>(
      x, smooth, qw, wsc, pd, pu, xdq, wdq, pu_bf, lp);
  gemm_kernel<<<dim3(COUT / 128, MTOK / 128), 256, 0, stream>>>(
      xdq, wdq, pu_bf, lp, bias, out);
}

// Round 5
// 256.231 us; speedup vs baseline: 1.1795x; 1.1795x over previous
//
#include <hip/hip_runtime.h>
#include <stdint.h>

typedef unsigned short u16;

#define MTOK 4096
#define CIN  3072
#define COUT 3072
#define RANK 32
#define KT48 48
#define RS   3136       // row stride for xdq/wdq (6272 B: gcd with 4096 = 128 -> good HBM channel spread)
#define LKSPLIT 16
#define LKC (CIN/LKSPLIT)   // 192 = 3 k-tiles

// prep grid: [0, LORA_BLK) fused lora+quant panels, rest wdq rows
#define LORA_BLK (MTOK/128*LKSPLIT)  // 512
#define WDQ_BLK COUT                 // 3072

// Workspace:
//   xdq:     (MTOK, RS) bf16    quantized activations (cols 0..3071 valid)
//   wdq:     (COUT, RS) bf16    dequantized weights
//   pu_bf:   (COUT, RANK) bf16  proj_up cast
//   lora_bf: (MTOK, RANK) bf16  reduced lora activations
//   lp:      (LKSPLIT, MTOK, RANK) f32  lora K-split partials (deterministic)

typedef __attribute__((ext_vector_type(8))) short bf16x8;
typedef __attribute__((ext_vector_type(4))) float f32x4;

__device__ __forceinline__ u16 f2bf(float f) {
  union { float f; unsigned u; } v; v.f = f;
  unsigned r = v.u + 0x7FFFu + ((v.u >> 16) & 1u);  // RNE
  return (u16)(r >> 16);
}

__device__ __forceinline__ void gload_lds16(const void* g, void* l) {
  __builtin_amdgcn_global_load_lds(
      (const __attribute__((address_space(1))) unsigned int*)g,
      (__attribute__((address_space(3))) unsigned int*)l, 16, 0, 0);
}

__device__ __forceinline__ float quant1(float xs, float ascale, float qd) {
  float q = rintf(xs / qd);                      // jnp.round = RNE, exact IEEE div
  q = fminf(fmaxf(q, -8.f), 7.f);
  return q * ascale;
}

// Fused prep: lora-panel blocks (also emit quantized xdq for their chunk — x read ONCE)
// + weight dequant rows.
__global__ __launch_bounds__(256) void prep_kernel(
    const float* __restrict__ x, const float* __restrict__ smooth,
    const int* __restrict__ qw, const float* __restrict__ wsc,
    const float* __restrict__ pd, const float* __restrict__ pu,
    u16* __restrict__ xdq, u16* __restrict__ wdq, u16* __restrict__ pu_bf,
    float* __restrict__ lp)
{
  const int b = blockIdx.x;
  const int t = threadIdx.x;

  if (b < LORA_BLK) {
    // ---- panel (m0..m0+128) x K-chunk kblk: quantize to xdq + lora partial to lp ----
    __shared__ __align__(16) u16 sA[128 * 64];
    __shared__ __align__(16) u16 sB[32 * 64];
    const int m0 = (b >> 4) * 128;        // 32 m-panels
    const int kblk = b & 15;              // 16 K-splits
    const int wave = t >> 6, lane = t & 63;
    const int lm = lane & 15, lkq = (lane >> 4) * 8;

    f32x4 acc[2][2];
    const f32x4 fz = {0.f, 0.f, 0.f, 0.f};
#pragma unroll
    for (int i = 0; i < 2; ++i)
#pragma unroll
      for (int j = 0; j < 2; ++j) acc[i][j] = fz;

    for (int kt = 0; kt < LKC / 64; ++kt) {
      const int k0 = kblk * LKC + kt * 64;
      const int col = (t & 15) * 4;       // 16 lanes x 4 = one 64-quant-group per row
#pragma unroll
      for (int it = 0; it < 8; ++it) {
        const int row = it * 16 + (t >> 4);
        const float4 xv = *(const float4*)(x + (size_t)(m0 + row) * CIN + k0 + col);
        const float4 sv = *(const float4*)(smooth + k0 + col);
        const float xs0 = xv.x / sv.x, xs1 = xv.y / sv.y;
        const float xs2 = xv.z / sv.z, xs3 = xv.w / sv.w;
        // bf16 xs -> LDS for the lora MFMA
        ushort4 ov;
        ov.x = f2bf(xs0); ov.y = f2bf(xs1); ov.z = f2bf(xs2); ov.w = f2bf(xs3);
        *(ushort4*)&sA[row * 64 + col] = ov;
        // group quant (amax across the 16-lane subgroup) -> xdq
        float a = fmaxf(fmaxf(fabsf(xs0), fabsf(xs1)), fmaxf(fabsf(xs2), fabsf(xs3)));
#pragma unroll
        for (int off = 1; off < 16; off <<= 1) a = fmaxf(a, __shfl_xor(a, off));
        const float ascale = a / 7.0f;
        const float qd = fmaxf(ascale, 1e-8f);
        ushort4 oq;
        oq.x = f2bf(quant1(xs0, ascale, qd));
        oq.y = f2bf(quant1(xs1, ascale, qd));
        oq.z = f2bf(quant1(xs2, ascale, qd));
        oq.w = f2bf(quant1(xs3, ascale, qd));
        *(ushort4*)(xdq + (size_t)(m0 + row) * RS + k0 + col) = oq;
      }
#pragma unroll
      for (int i = 0; i < 8; ++i) {
        const int idx = i * 256 + t;
        const int k = idx >> 5, r = idx & 31;
        sB[r * 64 + k] = f2bf(pd[(size_t)(k0 + k) * RANK + r]);
      }
      __syncthreads();
#pragma unroll
      for (int kk = 0; kk < 2; ++kk) {
        const int ko = kk * 32 + lkq;
        bf16x8 af[2], bfr[2];
#pragma unroll
        for (int i = 0; i < 2; ++i)
          af[i] = *(const bf16x8*)&sA[(wave * 32 + i * 16 + lm) * 64 + ko];
#pragma unroll
        for (int j = 0; j < 2; ++j)
          bfr[j] = *(const bf16x8*)&sB[(j * 16 + lm) * 64 + ko];
#pragma unroll
        for (int i = 0; i < 2; ++i)
#pragma unroll
          for (int j = 0; j < 2; ++j)
            acc[i][j] = __builtin_amdgcn_mfma_f32_16x16x32_bf16(af[i], bfr[j], acc[i][j], 0, 0, 0);
      }
      __syncthreads();
    }
    float* lpk = lp + (size_t)kblk * MTOK * RANK;
#pragma unroll
    for (int i = 0; i < 2; ++i)
#pragma unroll
      for (int j = 0; j < 2; ++j) {
        const int col = j * 16 + lm;
        const int row0 = m0 + wave * 32 + i * 16 + (lane >> 4) * 4;
#pragma unroll
        for (int r = 0; r < 4; ++r)
          lpk[(size_t)(row0 + r) * RANK + col] = acc[i][j][r];
      }
  } else {
    // ---- weight dequant row + pu_bf cast ----
    const int o = b - LORA_BLK;
    const int4* qrow = (const int4*)(qw + (size_t)o * CIN);
    u16* orow = wdq + (size_t)o * RS;
#pragma unroll
    for (int p = 0; p < 3; ++p) {
      const int c4 = p * 256 + t;
      const int g = (c4 * 4) >> 6;
      const float ws = wsc[g * COUT + o];    // wscales is (G, C_out)
      const int4 qv = qrow[c4];
      ushort4 ov;
      ov.x = f2bf((float)(qv.x - 8) * ws);
      ov.y = f2bf((float)(qv.y - 8) * ws);
      ov.z = f2bf((float)(qv.z - 8) * ws);
      ov.w = f2bf((float)(qv.w - 8) * ws);
      ((ushort4*)orow)[c4] = ov;
    }
    if (t < RANK) pu_bf[(size_t)o * RANK + t] = f2bf(pu[(size_t)o * RANK + t]);
  }
}

// Reduce lora K-split partials -> bf16 lora_bf (M, 32).
__global__ __launch_bounds__(256) void lora_fix_kernel(
    const float* __restrict__ lp, u16* __restrict__ lora_bf)
{
  const int idx = blockIdx.x * 256 + threadIdx.x;   // MTOK*RANK
  const int m = idx >> 5, c = idx & 31;
  float s = 0.f;
#pragma unroll
  for (int k = 0; k < LKSPLIT; ++k) s += lp[((size_t)k * MTOK + m) * RANK + c];
  lora_bf[(size_t)m * RANK + c] = f2bf(s);
}

// Main GEMM: 128x128 bf16 MFMA, K=3072, XOR-swizzled LDS, lora-MFMA + bias epilogue.
__global__ __launch_bounds__(256) void gemm_kernel(
    const u16* __restrict__ xdq, const u16* __restrict__ wdq,
    const u16* __restrict__ pu_bf, const u16* __restrict__ lora_bf,
    const float* __restrict__ bias, float* __restrict__ out)
{
  __shared__ __align__(16) u16 sA[128 * 64];
  __shared__ __align__(16) u16 sB[128 * 64];
  const int t = threadIdx.x;
  const int wave = t >> 6, lane = t & 63;
  const int wm = wave >> 1, wn = wave & 1;           // 2x2 wave grid, 64x64 each
  const int m0 = blockIdx.y * 128, n0 = blockIdx.x * 128;
  const int lrow = lane >> 3;                        // 0..7 row within 8-row chunk
  const int gcol = ((lane & 7) ^ lrow) * 8;          // swizzled global col block

  f32x4 acc[4][4];
  const f32x4 fz = {0.f, 0.f, 0.f, 0.f};
#pragma unroll
  for (int i = 0; i < 4; ++i)
#pragma unroll
    for (int j = 0; j < 4; ++j) acc[i][j] = fz;

  const int lm = lane & 15;
  const int xs7 = lm & 7;                            // row&7 for fragment rows
  const int q4 = lane >> 4;

  for (int kt = 0; kt < KT48; ++kt) {
    const u16* Ab = xdq + (size_t)m0 * RS + kt * 64;
    const u16* Bb = wdq + (size_t)n0 * RS + kt * 64;
#pragma unroll
    for (int r = 0; r < 4; ++r) {
      const int ci = wave * 4 + r;                   // 1KB chunk id (16 per tile)
      const int row = ci * 8 + lrow;
      gload_lds16(Ab + (size_t)row * RS + gcol, &sA[ci * 512 + lane * 8]);
      gload_lds16(Bb + (size_t)row * RS + gcol, &sB[ci * 512 + lane * 8]);
    }
    __syncthreads();   // drains vmcnt incl. global_load_lds
#pragma unroll
    for (int kk = 0; kk < 2; ++kk) {
      const int csw = ((kk * 4 + q4) ^ xs7) * 8;     // swizzled LDS col for this k-block
      bf16x8 af[4], bfr[4];
#pragma unroll
      for (int i = 0; i < 4; ++i)
        af[i] = *(const bf16x8*)&sA[(wm * 64 + i * 16 + lm) * 64 + csw];
#pragma unroll
      for (int j = 0; j < 4; ++j)
        bfr[j] = *(const bf16x8*)&sB[(wn * 64 + j * 16 + lm) * 64 + csw];
#pragma unroll
      for (int i = 0; i < 4; ++i)
#pragma unroll
        for (int j = 0; j < 4; ++j)
          acc[i][j] = __builtin_amdgcn_mfma_f32_16x16x32_bf16(af[i], bfr[j], acc[i][j], 0, 0, 0);
    }
    __syncthreads();
  }

  // ---- lora epilogue: acc += lora_act(128x32) . proj_up(128x32)^T (bf16, L2-hot) ----
  bf16x8 afl[4], bfl[4];
#pragma unroll
  for (int i = 0; i < 4; ++i) {
    const int arow = m0 + wm * 64 + i * 16 + lm;
    afl[i] = *(const bf16x8*)(lora_bf + (size_t)arow * RANK + q4 * 8);
  }
#pragma unroll
  for (int j = 0; j < 4; ++j) {
    const int bcol = n0 + wn * 64 + j * 16 + lm;
    bfl[j] = *(const bf16x8*)(pu_bf + (size_t)bcol * RANK + q4 * 8);
  }
#pragma unroll
  for (int i = 0; i < 4; ++i)
#pragma unroll
    for (int j = 0; j < 4; ++j)
      acc[i][j] = __builtin_amdgcn_mfma_f32_16x16x32_bf16(afl[i], bfl[j], acc[i][j], 0, 0, 0);

  // store: C/D layout col=lane&15, row=(lane>>4)*4+reg  [m89-verified]
#pragma unroll
  for (int j = 0; j < 4; ++j) {
    const int col = n0 + wn * 64 + j * 16 + lm;
    const float bv = bias[col];
#pragma unroll
    for (int i = 0; i < 4; ++i) {
      const int row0 = m0 + wm * 64 + i * 16 + (lane >> 4) * 4;
#pragma unroll
      for (int r = 0; r < 4; ++r)
        out[(size_t)(row0 + r) * COUT + col] = acc[i][j][r] + bv;
    }
  }
}

extern "C" void kernel_launch(void* const* d_in, const int* in_sizes, int n_in,
                              void* d_out, int out_size, void* d_ws, size_t ws_size,
                              hipStream_t stream) {
  const float* x      = (const float*)d_in[0];
  const int*   qw     = (const int*)d_in[1];
  const float* wsc    = (const float*)d_in[2];
  const float* smooth = (const float*)d_in[3];
  const float* pd     = (const float*)d_in[4];
  const float* pu     = (const float*)d_in[5];
  const float* bias   = (const float*)d_in[6];
  float* out = (float*)d_out;

  u16* xdq     = (u16*)d_ws;                               // 4096*3136*2 = 25.7 MB
  u16* wdq     = xdq + (size_t)MTOK * RS;                  // 3072*3136*2 = 19.3 MB
  u16* pu_bf   = wdq + (size_t)COUT * RS;                  // 3072*32*2   = 0.2 MB
  u16* lora_bf = pu_bf + (size_t)COUT * RANK;              // 4096*32*2   = 0.3 MB
  float* lp    = (float*)(lora_bf + (size_t)MTOK * RANK);  // 16*4096*32*4 = 8.4 MB

  prep_kernel<<<LORA_BLK + WDQ_BLK, 256, 0, stream>>>(
      x, smooth, qw, wsc, pd, pu, xdq, wdq, pu_bf, lp);
  lora_fix_kernel<<<MTOK * RANK / 256, 256, 0, stream>>>(lp, lora_bf);
  gemm_kernel<<<dim3(COUT / 128, MTOK / 128), 256, 0, stream>>>(
      xdq, wdq, pu_bf, lora_bf, bias, out);
}